// Round 8
// baseline (73.711 us; speedup 1.0000x reference)
//
#include <hip/hip_runtime.h>

// CSR SpMM, sum aggregation: out[i] = sum_{j in [rowptr[i], rowptr[i+1])} x[col[j]]
// x: [N=50000, D=128] f32, rowptr: [N+1] i32, col: [E=1.6M] i32, out: [N, D] f32.
//
// Regime (rounds 1,4-7): scattered-gather line throughput is latency-bound and
// scales with RESIDENT WAVES (8.8-11.6 cy/line at 66-36% occupancy), not with
// in-code MLP. bf16 rows = 256B = 2 lines/edge = 3.2M touches. This round
// raises occupancy: 4 consecutive rows per wave, all 5 rowptr boundaries
// loaded in one instruction (lanes 0-4 + shfl broadcast), amortizing the wave
// prologue/retire 4x. Gather core is round 5's proven 16-edge / 4-slot loop.

typedef float f32x4 __attribute__((ext_vector_type(4)));
typedef unsigned int u32;

// ---- x (f32) -> bf16-packed (u32 holds feats 2k,2k+1), RNE rounding ----
__global__ __launch_bounds__(256) void cvt_bf16_kernel(
    const float2* __restrict__ x2, u32* __restrict__ xb, int npairs)
{
    for (int i = blockIdx.x * 256 + threadIdx.x; i < npairs; i += gridDim.x * 256) {
        const float2 f = x2[i];
        u32 a = __float_as_uint(f.x);
        a = (a + 0x7FFFu + ((a >> 16) & 1u)) >> 16;
        u32 b = __float_as_uint(f.y);
        b = (b + 0x7FFFu + ((b >> 16) & 1u)) & 0xFFFF0000u;
        xb[i] = a | b;
    }
}

__device__ __forceinline__ void addv(float* acc, const uint4 v) {
    acc[0] += __uint_as_float(v.x << 16);
    acc[1] += __uint_as_float(v.x & 0xFFFF0000u);
    acc[2] += __uint_as_float(v.y << 16);
    acc[3] += __uint_as_float(v.y & 0xFFFF0000u);
    acc[4] += __uint_as_float(v.z << 16);
    acc[5] += __uint_as_float(v.z & 0xFFFF0000u);
    acc[6] += __uint_as_float(v.w << 16);
    acc[7] += __uint_as_float(v.w & 0xFFFF0000u);
}

// ---- 4 consecutive rows per wave over bf16 x ----
__global__ __launch_bounds__(256) void spmm_row4_kernel(
    const uint4* __restrict__ xb,      // [N][16] : 16 x 16B = 256B bf16 row
    const int*   __restrict__ rowptr,
    const int*   __restrict__ col,
    float*       __restrict__ out,     // [N][128] f32
    int n_nodes)
{
    const int wave = threadIdx.x >> 6;
    const int lane = threadIdx.x & 63;
    const int sub  = lane >> 4;              // 0..3 edge slot
    const int l16  = lane & 15;              // which 16B slice of the row
    const int base = (blockIdx.x * 4 + wave) * 4;   // first of 4 rows
    if (base >= n_nodes) return;

    // One load for all row boundaries: lanes 0..4 read rowptr[base+lane].
    int rp = 0;
    if (lane < 5) {
        int idx = base + lane;
        if (idx > n_nodes) idx = n_nodes;
        rp = rowptr[idx];
    }

    const uint4* xbl = xb + l16;

    #pragma unroll
    for (int k = 0; k < 4; ++k) {
        const int row = base + k;
        if (row >= n_nodes) break;           // wave-uniform
        const int r0 = __shfl(rp, k, 64);
        const int r1 = __shfl(rp, k + 1, 64);

        float acc[8] = {0.f, 0.f, 0.f, 0.f, 0.f, 0.f, 0.f, 0.f};

        int j = r0;
        // Main: 16 edges per iteration, 4 independent gathers in flight/lane.
        for (; j + 16 <= r1; j += 16) {
            const int c0 = __builtin_nontemporal_load(col + j + sub + 0);
            const int c1 = __builtin_nontemporal_load(col + j + sub + 4);
            const int c2 = __builtin_nontemporal_load(col + j + sub + 8);
            const int c3 = __builtin_nontemporal_load(col + j + sub + 12);
            const uint4 v0 = xbl[(size_t)c0 * 16];
            const uint4 v1 = xbl[(size_t)c1 * 16];
            const uint4 v2 = xbl[(size_t)c2 * 16];
            const uint4 v3 = xbl[(size_t)c3 * 16];
            addv(acc, v0); addv(acc, v1); addv(acc, v2); addv(acc, v3);
        }
        // Mid: 4 edges per iteration.
        for (; j + 4 <= r1; j += 4) {
            const int c = __builtin_nontemporal_load(col + j + sub);
            addv(acc, xbl[(size_t)c * 16]);
        }
        // Tail: < 4 edges, predicated per slot.
        if (j + sub < r1) {
            const int c = __builtin_nontemporal_load(col + j + sub);
            addv(acc, xbl[(size_t)c * 16]);
        }

        // Reduce the 4 edge slots (lanes l16, l16+16, l16+32, l16+48).
        #pragma unroll
        for (int q = 0; q < 8; ++q) {
            acc[q] += __shfl_xor(acc[q], 16, 64);
            acc[q] += __shfl_xor(acc[q], 32, 64);
        }

        if (sub == 0) {
            float* dst = out + (size_t)row * 128 + l16 * 8;
            __builtin_nontemporal_store((f32x4){acc[0], acc[1], acc[2], acc[3]},
                                        (f32x4*)dst);
            __builtin_nontemporal_store((f32x4){acc[4], acc[5], acc[6], acc[7]},
                                        (f32x4*)(dst + 4));
        }
    }
}

// ---- fallback: fp32 row-per-wave (if ws too small for bf16 copy) ----
__global__ __launch_bounds__(256) void spmm_f32_kernel(
    const f32x4* __restrict__ x4,
    const int*   __restrict__ rowptr,
    const int*   __restrict__ col,
    f32x4*       __restrict__ out4,
    int n_nodes)
{
    const int lane = threadIdx.x & 31;
    const int grp  = threadIdx.x >> 5;
    const int row  = blockIdx.x * 8 + grp;
    if (row >= n_nodes) return;

    const int r1 = rowptr[row + 1];
    int j = rowptr[row];
    f32x4 acc = {0.f, 0.f, 0.f, 0.f};
    for (; j + 4 <= r1; j += 4) {
        const int c0 = col[j + 0];
        const int c1 = col[j + 1];
        const int c2 = col[j + 2];
        const int c3 = col[j + 3];
        f32x4 a = x4[(size_t)c0 * 32 + lane];
        f32x4 b = x4[(size_t)c1 * 32 + lane];
        f32x4 c = x4[(size_t)c2 * 32 + lane];
        f32x4 d = x4[(size_t)c3 * 32 + lane];
        acc += a; acc += b; acc += c; acc += d;
    }
    for (; j < r1; ++j) acc += x4[(size_t)col[j] * 32 + lane];
    out4[(size_t)row * 32 + lane] = acc;
}

extern "C" void kernel_launch(void* const* d_in, const int* in_sizes, int n_in,
                              void* d_out, int out_size, void* d_ws, size_t ws_size,
                              hipStream_t stream) {
    const float* x      = (const float*)d_in[0];
    const int*   rowptr = (const int*)d_in[1];
    const int*   col    = (const int*)d_in[2];
    float*       out    = (float*)d_out;

    const int n_nodes = in_sizes[1] - 1;
    const int n_feats = (n_nodes > 0) ? in_sizes[0] / n_nodes : 0;   // 128
    const size_t xb_bytes = (size_t)in_sizes[0] * 2;                  // bf16 copy

    if (ws_size >= xb_bytes && n_feats == 128) {
        u32* xb = (u32*)d_ws;
        const int npairs = in_sizes[0] / 2;
        cvt_bf16_kernel<<<2048, 256, 0, stream>>>((const float2*)x, xb, npairs);
        const int blocks = (n_nodes + 15) / 16;   // 16 rows per block (4/wave)
        spmm_row4_kernel<<<blocks, 256, 0, stream>>>(
            (const uint4*)xb, rowptr, col, out, n_nodes);
    } else {
        const int blocks = (n_nodes + 7) / 8;
        spmm_f32_kernel<<<blocks, 256, 0, stream>>>(
            (const f32x4*)x, rowptr, col, (f32x4*)out, n_nodes);
    }
}

// Round 9
// 66.633 us; speedup vs baseline: 1.1062x; 1.1062x over previous
//
#include <hip/hip_runtime.h>

// CSR SpMM, sum aggregation: out[i] = sum_{j in [rowptr[i], rowptr[i+1])} x[col[j]]
// x: [N=50000, D=128] f32, rowptr: [N+1] i32, col: [E=1.6M] i32, out: [N, D] f32.
//
// Validated regime (rounds 1,4-8): cost ~= 85 cy per 64-divergent-lane vmem
// instruction (1 KB gather payload each), independent of cache hit level,
// request size, MLP depth; saturated above ~53% occupancy. bf16 gather
// stream = 410 MB = 400K instructions ~= 55 us -> this config is the floor.
//
// Pass 1: stream-convert x to bf16 (RNE) in d_ws.
// Pass 2: one row per wave; 16 lanes x 16B = one 256B bf16 row per edge;
// 4 edge slots -> 16 edges/iter; shfl_xor reduce; nontemporal col/out.

typedef float f32x4 __attribute__((ext_vector_type(4)));
typedef unsigned int u32;

// ---- x (f32) -> bf16-packed (u32 holds feats 2k,2k+1), RNE rounding ----
__global__ __launch_bounds__(256) void cvt_bf16_kernel(
    const float2* __restrict__ x2, u32* __restrict__ xb, int npairs)
{
    for (int i = blockIdx.x * 256 + threadIdx.x; i < npairs; i += gridDim.x * 256) {
        const float2 f = x2[i];
        u32 a = __float_as_uint(f.x);
        a = (a + 0x7FFFu + ((a >> 16) & 1u)) >> 16;
        u32 b = __float_as_uint(f.y);
        b = (b + 0x7FFFu + ((b >> 16) & 1u)) & 0xFFFF0000u;
        xb[i] = a | b;
    }
}

__device__ __forceinline__ void addv(float* acc, const uint4 v) {
    acc[0] += __uint_as_float(v.x << 16);
    acc[1] += __uint_as_float(v.x & 0xFFFF0000u);
    acc[2] += __uint_as_float(v.y << 16);
    acc[3] += __uint_as_float(v.y & 0xFFFF0000u);
    acc[4] += __uint_as_float(v.z << 16);
    acc[5] += __uint_as_float(v.z & 0xFFFF0000u);
    acc[6] += __uint_as_float(v.w << 16);
    acc[7] += __uint_as_float(v.w & 0xFFFF0000u);
}

// ---- one row per wave over bf16 x ----
__global__ __launch_bounds__(256) void spmm_rowwave_kernel(
    const uint4* __restrict__ xb,      // [N][16] : 16 x 16B = 256B bf16 row
    const int*   __restrict__ rowptr,
    const int*   __restrict__ col,
    float*       __restrict__ out,     // [N][128] f32
    int n_nodes)
{
    const int wave = threadIdx.x >> 6;       // 0..3 row within block
    const int lane = threadIdx.x & 63;
    const int sub  = lane >> 4;              // 0..3 edge slot
    const int l16  = lane & 15;              // which 16B slice of the row
    const int row  = blockIdx.x * 4 + wave;
    if (row >= n_nodes) return;

    const uint4* xbl = xb + l16;
    const int r0 = rowptr[row];
    const int r1 = rowptr[row + 1];

    float acc[8] = {0.f, 0.f, 0.f, 0.f, 0.f, 0.f, 0.f, 0.f};

    int j = r0;
    // Main: 16 edges per iteration (4 per edge slot), 4 loads in flight/lane.
    for (; j + 16 <= r1; j += 16) {
        const int c0 = __builtin_nontemporal_load(col + j + sub + 0);
        const int c1 = __builtin_nontemporal_load(col + j + sub + 4);
        const int c2 = __builtin_nontemporal_load(col + j + sub + 8);
        const int c3 = __builtin_nontemporal_load(col + j + sub + 12);
        const uint4 v0 = xbl[(size_t)c0 * 16];
        const uint4 v1 = xbl[(size_t)c1 * 16];
        const uint4 v2 = xbl[(size_t)c2 * 16];
        const uint4 v3 = xbl[(size_t)c3 * 16];
        addv(acc, v0); addv(acc, v1); addv(acc, v2); addv(acc, v3);
    }
    // Mid: 4 edges per iteration.
    for (; j + 4 <= r1; j += 4) {
        const int c = __builtin_nontemporal_load(col + j + sub);
        addv(acc, xbl[(size_t)c * 16]);
    }
    // Tail: < 4 edges, predicated per slot.
    if (j + sub < r1) {
        const int c = __builtin_nontemporal_load(col + j + sub);
        addv(acc, xbl[(size_t)c * 16]);
    }

    // Reduce the 4 edge slots (lanes l16, l16+16, l16+32, l16+48).
    #pragma unroll
    for (int k = 0; k < 8; ++k) {
        acc[k] += __shfl_xor(acc[k], 16, 64);
        acc[k] += __shfl_xor(acc[k], 32, 64);
    }

    if (sub == 0) {
        float* dst = out + (size_t)row * 128 + l16 * 8;
        __builtin_nontemporal_store((f32x4){acc[0], acc[1], acc[2], acc[3]}, (f32x4*)dst);
        __builtin_nontemporal_store((f32x4){acc[4], acc[5], acc[6], acc[7]}, (f32x4*)(dst + 4));
    }
}

// ---- fallback: fp32 row-per-wave (if ws too small for bf16 copy) ----
__global__ __launch_bounds__(256) void spmm_f32_kernel(
    const f32x4* __restrict__ x4,
    const int*   __restrict__ rowptr,
    const int*   __restrict__ col,
    f32x4*       __restrict__ out4,
    int n_nodes)
{
    const int lane = threadIdx.x & 31;
    const int grp  = threadIdx.x >> 5;
    const int row  = blockIdx.x * 8 + grp;
    if (row >= n_nodes) return;

    const int r1 = rowptr[row + 1];
    int j = rowptr[row];
    f32x4 acc = {0.f, 0.f, 0.f, 0.f};
    for (; j + 4 <= r1; j += 4) {
        const int c0 = col[j + 0];
        const int c1 = col[j + 1];
        const int c2 = col[j + 2];
        const int c3 = col[j + 3];
        f32x4 a = x4[(size_t)c0 * 32 + lane];
        f32x4 b = x4[(size_t)c1 * 32 + lane];
        f32x4 c = x4[(size_t)c2 * 32 + lane];
        f32x4 d = x4[(size_t)c3 * 32 + lane];
        acc += a; acc += b; acc += c; acc += d;
    }
    for (; j < r1; ++j) acc += x4[(size_t)col[j] * 32 + lane];
    out4[(size_t)row * 32 + lane] = acc;
}

extern "C" void kernel_launch(void* const* d_in, const int* in_sizes, int n_in,
                              void* d_out, int out_size, void* d_ws, size_t ws_size,
                              hipStream_t stream) {
    const float* x      = (const float*)d_in[0];
    const int*   rowptr = (const int*)d_in[1];
    const int*   col    = (const int*)d_in[2];
    float*       out    = (float*)d_out;

    const int n_nodes = in_sizes[1] - 1;
    const int n_feats = (n_nodes > 0) ? in_sizes[0] / n_nodes : 0;   // 128
    const size_t xb_bytes = (size_t)in_sizes[0] * 2;                  // bf16 copy

    if (ws_size >= xb_bytes && n_feats == 128) {
        u32* xb = (u32*)d_ws;
        const int npairs = in_sizes[0] / 2;
        cvt_bf16_kernel<<<2048, 256, 0, stream>>>((const float2*)x, xb, npairs);
        const int blocks = (n_nodes + 3) / 4;
        spmm_rowwave_kernel<<<blocks, 256, 0, stream>>>(
            (const uint4*)xb, rowptr, col, out, n_nodes);
    } else {
        const int blocks = (n_nodes + 7) / 8;
        spmm_f32_kernel<<<blocks, 256, 0, stream>>>(
            (const f32x4*)x, rowptr, col, (f32x4*)out, n_nodes);
    }
}